// Round 9
// baseline (18176.880 us; speedup 1.0000x reference)
//
#include <hip/hip_runtime.h>
#include <hip/hip_cooperative_groups.h>
#include <cstddef>

// Problem constants (B,S,D,H,L) = (32,512,1024,1024,2)
#define Bq 32
#define Sq 512
#define Hq 1024
#define G4q 4096          // 4*H
#define CHUNKq 128        // timesteps per gates chunk
#define NCHq (Sq / CHUNKq)
#define BHq (Bq * Hq)     // 32768

// ---------------------------------------------------------------------------
// Input-projection GEMM. C-write uses the scan-coalesced gates layout:
//   gates[(((tt*256 + j4)*4 + p)*32 + b)*4 + jj]   (p = gate type, j4 = j>>2)
// so each scan block's per-step slice is one contiguous 2 KB region.
// block(0,0) zeroes the scan's barrier words (ws re-poisoned every launch).
// ---------------------------------------------------------------------------
__global__ __launch_bounds__(256)
void gemm_xproj(const float* __restrict__ A,
                const float* __restrict__ Wm,
                const float* __restrict__ bias,
                float* __restrict__ gates,
                unsigned int* __restrict__ bar,
                int s0)
{
    __shared__ float As[8][132];   // [k][m] transposed
    __shared__ float Bs[8][132];   // [k][n]

    const int tid = threadIdx.x;
    if (blockIdx.x == 0 && blockIdx.y == 0 && tid < 18)
        bar[tid * 32] = 0u;        // 16 group counters + root + generation

    const int tr = tid >> 4;
    const int tc = tid & 15;
    const int m0 = blockIdx.y * 128;
    const int n0 = blockIdx.x * 128;

    float acc[8][8];
    #pragma unroll
    for (int i = 0; i < 8; ++i)
        #pragma unroll
        for (int j = 0; j < 8; ++j) acc[i][j] = 0.f;

    const int a_m  = tid >> 1;
    const int a_k4 = (tid & 1) * 4;
    const int b_k  = tid >> 5;
    const int b_n4 = (tid & 31) * 4;

    const int am_g = m0 + a_m;
    const int ab = am_g >> 7;
    const int as = s0 + (am_g & 127);
    const float* Arow = A + ((size_t)ab * Sq + as) * 1024;

    for (int k0 = 0; k0 < 1024; k0 += 8) {
        float4 av = *(const float4*)(Arow + k0 + a_k4);
        float4 bv = *(const float4*)(Wm + (size_t)(k0 + b_k) * G4q + n0 + b_n4);
        __syncthreads();
        As[a_k4 + 0][a_m] = av.x;
        As[a_k4 + 1][a_m] = av.y;
        As[a_k4 + 2][a_m] = av.z;
        As[a_k4 + 3][a_m] = av.w;
        *(float4*)(&Bs[b_k][b_n4]) = bv;
        __syncthreads();
        #pragma unroll
        for (int kk = 0; kk < 8; ++kk) {
            float4 a0 = *(const float4*)(&As[kk][tr * 8]);
            float4 a1 = *(const float4*)(&As[kk][tr * 8 + 4]);
            float4 b0 = *(const float4*)(&Bs[kk][tc * 8]);
            float4 b1 = *(const float4*)(&Bs[kk][tc * 8 + 4]);
            float avv[8] = {a0.x, a0.y, a0.z, a0.w, a1.x, a1.y, a1.z, a1.w};
            float bvv[8] = {b0.x, b0.y, b0.z, b0.w, b1.x, b1.y, b1.z, b1.w};
            #pragma unroll
            for (int i = 0; i < 8; ++i)
                #pragma unroll
                for (int j = 0; j < 8; ++j)
                    acc[i][j] += avv[i] * bvv[j];
        }
    }

    float bv8[8];
    *(float4*)(bv8)     = *(const float4*)(bias + n0 + tc * 8);
    *(float4*)(bv8 + 4) = *(const float4*)(bias + n0 + tc * 8 + 4);

    const int p  = n0 >> 10;                 // gate type, constant per block
    const int nn = (n0 & 1023) + tc * 8;     // 0..1016, 8-aligned
    const int j4 = nn >> 2;                  // first j-quad of this thread

    #pragma unroll
    for (int i = 0; i < 8; ++i) {
        const int m = m0 + tr * 8 + i;
        const int b = m >> 7;
        const int r = m & 127;               // tt within chunk
        float* outp = gates +
            ((((size_t)r * 256 + j4) * 4 + p) * 32 + b) * 4;
        float4 v0 = {acc[i][0] + bv8[0], acc[i][1] + bv8[1],
                     acc[i][2] + bv8[2], acc[i][3] + bv8[3]};
        float4 v1 = {acc[i][4] + bv8[4], acc[i][5] + bv8[5],
                     acc[i][6] + bv8[6], acc[i][7] + bv8[7]};
        *(float4*)outp         = v0;
        *(float4*)(outp + 512) = v1;         // j4+1 stride = 4*32*4
    }
}

// ---------------------------------------------------------------------------
// R6 scan = R5 + coalesced gates + 1-step-ahead register prefetch.
// 256 blocks x 512 threads; block owns cells j0 = blockIdx.x*4 .. +4.
// Thread (kg=lane, bg=wave): k in [16kg,16kg+16) x b in [4bg,4bg+4).
// Whh staged once in swizzled LDS (64 KB). Full-wave recursive-halving
// reduce-scatter leaves lane L the gate partial for bitrev6(L)=(bi,ct,jj);
// 3 shfls gather the ct-quad; only ct==0 lanes (16/wave) load gates, update
// c, and store h/y. Gates for step tt+1 are prefetched into registers right
// after the h waitcnt -> a full step of slack hides HBM latency, removing
// per-block jitter from the max-of-256 barrier critical path.
// Barrier: two-level monotonic arrive (relaxed agent atomics, bounded spin).
// ---------------------------------------------------------------------------
__global__ __launch_bounds__(512, 2)
void lstm_scan(const float* __restrict__ gates,
               const float* __restrict__ Whh,
               float* __restrict__ hbuf,     // [2][H][B] transposed, dbuf
               float* __restrict__ cstate,   // [B][H]
               float* __restrict__ y,        // [B][S][H]
               unsigned int* __restrict__ bar,
               int t0)
{
    __shared__ float4 Wlds[4096];   // 64 KB

    const int tid  = threadIdx.x;
    const int lane = tid & 63;
    const int bg   = tid >> 6;      // wave = batch group (4 batches)
    const int bk   = blockIdx.x;
    const int j0   = bk * 4;
    const int kg   = lane;          // k-group (16 k's)

    // --- stage Whh cols {s*Hq + j0 .. +4} into swizzled LDS (once) ---
    #pragma unroll
    for (int idx = tid; idx < 4096; idx += 512) {
        const int k  = idx >> 2;
        const int s  = idx & 3;
        const int kgs = k >> 4;
        const int slot = (s + (kgs >> 1)) & 3;
        Wlds[(((k & 15) * 64 + kgs) << 2) + slot] =
            *(const float4*)(Whh + (size_t)k * G4q + s * Hq + j0);
    }

    // lane roles from the bit-reversed reduction mapping: v = bitrev6(lane)
    const int bi = ((lane & 1) << 1) | ((lane >> 1) & 1);        // v[5:4]
    const int ct = (((lane >> 2) & 1) << 1) | ((lane >> 3) & 1); // v[3:2]
    const int jj = (((lane >> 4) & 1) << 1) | ((lane >> 5) & 1); // v[1:0]
    const int b  = bg * 4 + bi;
    const int j  = j0 + jj;
    const bool upd = (lane & 12) == 0;       // ct == 0 lanes

    float creg = cstate[b * Hq + j];

    // coalesced gates base for this update lane: [tt][bk][p][b][jj]
    const float* gbase = gates + ((size_t)bk * 4) * 128 + b * 4 + jj;
    #define GSTEP ((size_t)256 * 4 * 128)    // per-tt stride in floats

    // prefetch tt = 0
    float gpre0 = 0.f, gpre1 = 0.f, gpre2 = 0.f, gpre3 = 0.f;
    if (upd) {
        gpre0 = gbase[0];
        gpre1 = gbase[128];
        gpre2 = gbase[256];
        gpre3 = gbase[384];
    }

    __syncthreads();

    for (int tt = 0; tt < CHUNKq; ++tt) {
        const float* ht = hbuf + (tt & 1) * BHq;
        float* hw = hbuf + ((tt + 1) & 1) * BHq;

        // --- coherent h loads: 16 x dwordx4, one wait ---
        float4 hv[16];
        const float* hp = ht + kg * 16 * Bq + bg * 4;
        #pragma unroll
        for (int i = 0; i < 16; ++i) {
            asm volatile("global_load_dwordx4 %0, %1, off offset:%c2 sc0 sc1"
                         : "=v"(hv[i]) : "v"(hp), "n"(i * 128));
        }
        asm volatile("s_waitcnt vmcnt(0)" ::: "memory");
        __builtin_amdgcn_sched_barrier(0);

        // consume this step's prefetched gates; issue next step's
        const float g0 = gpre0, g1 = gpre1, g2 = gpre2, g3 = gpre3;
        const int tn = (tt < CHUNKq - 1) ? tt + 1 : tt;
        if (upd) {
            const float* gp = gbase + (size_t)tn * GSTEP;
            gpre0 = gp[0];
            gpre1 = gp[128];
            gpre2 = gp[256];
            gpre3 = gp[384];
        }

        // --- partials: work[bb*16 + s*4 + jjc] over this thread's 16 k ---
        float work[64];
        #pragma unroll
        for (int v = 0; v < 64; ++v) work[v] = 0.f;

        const float4* wrow = Wlds + (kg << 2);
        #pragma unroll
        for (int i = 0; i < 16; ++i) {
            const float4 h4 = hv[i];
            const float4* wr = wrow + i * 256;
            #pragma unroll
            for (int s = 0; s < 4; ++s) {
                const int slot = (s + (kg >> 1)) & 3;
                const float4 w4 = wr[slot];
                #pragma unroll
                for (int bb = 0; bb < 4; ++bb) {
                    const float hb = (bb == 0) ? h4.x : (bb == 1) ? h4.y
                                   : (bb == 2) ? h4.z : h4.w;
                    work[bb * 16 + s * 4 + 0] += hb * w4.x;
                    work[bb * 16 + s * 4 + 1] += hb * w4.y;
                    work[bb * 16 + s * 4 + 2] += hb * w4.z;
                    work[bb * 16 + s * 4 + 3] += hb * w4.w;
                }
            }
        }

        // --- full-wave recursive-halving reduce-scatter (static indices) ---
        #define RR(m, n)                                                     \
        {                                                                    \
            const bool hi = (lane & (m)) != 0;                               \
            _Pragma("unroll")                                                \
            for (int i = 0; i < (n); ++i) {                                  \
                const float send = hi ? work[i] : work[i + (n)];             \
                const float got  = __shfl_xor(send, (m), 64);                \
                const float keep = hi ? work[i + (n)] : work[i];             \
                work[i] = keep + got;                                        \
            }                                                                \
        }
        RR(1, 32) RR(2, 16) RR(4, 8) RR(8, 4) RR(16, 2) RR(32, 1)
        #undef RR

        // gather the ct-quad partials into the ct==0 lane
        const float a0 = work[0];
        const float a1 = __shfl_xor(work[0], 8, 64);    // partner ct^1
        const float a2 = __shfl_xor(work[0], 4, 64);    // partner ct^2
        const float a3 = __shfl_xor(work[0], 12, 64);   // partner ct^3

        if (upd) {
            const float gi = g0 + a0;
            const float gf = g1 + a1;
            const float gg = g2 + a2;
            const float go = g3 + a3;
            const float iv = 1.f / (1.f + expf(-gi));
            const float fv = 1.f / (1.f + expf(-gf));
            const float gv = tanhf(gg);
            const float ov = 1.f / (1.f + expf(-go));
            creg = fv * creg + iv * gv;
            const float hval = ov * tanhf(creg);
            __hip_atomic_store(hw + j * Bq + b, hval,
                               __ATOMIC_RELAXED, __HIP_MEMORY_SCOPE_AGENT);
            y[((size_t)b * Sq + (t0 + tt)) * Hq + j] = hval;
        }

        // --- grid barrier: drain stores, two-level monotonic arrive ---
        __syncthreads();   // emits s_waitcnt vmcnt(0) before s_barrier
        if (tid == 0) {
            const int gid = bk >> 4;
            unsigned int old = __hip_atomic_fetch_add(bar + gid * 32, 1u,
                                  __ATOMIC_RELAXED, __HIP_MEMORY_SCOPE_AGENT);
            if ((old & 15u) == 15u) {
                unsigned int r = __hip_atomic_fetch_add(bar + 16 * 32, 1u,
                                  __ATOMIC_RELAXED, __HIP_MEMORY_SCOPE_AGENT);
                if ((r & 15u) == 15u)
                    __hip_atomic_store(bar + 17 * 32, (unsigned int)(tt + 1),
                                  __ATOMIC_RELAXED, __HIP_MEMORY_SCOPE_AGENT);
            }
            unsigned int guard = 0;
            while (__hip_atomic_load(bar + 17 * 32, __ATOMIC_RELAXED,
                                     __HIP_MEMORY_SCOPE_AGENT)
                       < (unsigned int)(tt + 1)
                   && ++guard < (1u << 20))
                __builtin_amdgcn_s_sleep(1);
        }
        __syncthreads();
    }

    if (upd) cstate[b * Hq + j] = creg;
    #undef GSTEP
}

// ---------------------------------------------------------------------------
// tiny state-layout shims: [B][H] <-> transposed [H][B]
// ---------------------------------------------------------------------------
__global__ __launch_bounds__(256)
void h_to_t(const float* __restrict__ src, float* __restrict__ dst) {
    const int i = blockIdx.x * 256 + threadIdx.x;
    const int b = i >> 10, j = i & 1023;
    dst[j * Bq + b] = src[i];
}
__global__ __launch_bounds__(256)
void h_from_t(const float* __restrict__ src, float* __restrict__ dst) {
    const int i = blockIdx.x * 256 + threadIdx.x;
    const int b = i >> 10, j = i & 1023;
    dst[i] = src[j * Bq + b];
}

// ---------------------------------------------------------------------------
extern "C" void kernel_launch(void* const* d_in, const int* in_sizes, int n_in,
                              void* d_out, int out_size, void* d_ws, size_t ws_size,
                              hipStream_t stream)
{
    const float* x    = (const float*)d_in[0];
    const float* h0   = (const float*)d_in[1];
    const float* c0   = (const float*)d_in[2];
    const float* wih0 = (const float*)d_in[3];
    const float* whh0 = (const float*)d_in[4];
    const float* b0   = (const float*)d_in[5];
    const float* wih1 = (const float*)d_in[6];
    const float* whh1 = (const float*)d_in[7];
    const float* b1   = (const float*)d_in[8];

    float* out = (float*)d_out;
    float* y1  = out;                                  // [B,S,H]
    float* hn  = out + (size_t)Bq * Sq * Hq;           // [2,B,H]
    float* cn  = hn + 2 * BHq;                         // [2,B,H]

    float* ws    = (float*)d_ws;
    float* gates = ws;                                  // CHUNK*B*4H floats
    float* hbuf  = gates + (size_t)CHUNKq * Bq * G4q;   // 2*B*H
    float* cst   = hbuf + 2 * BHq;                      // B*H
    unsigned int* bar = (unsigned int*)(cst + BHq);     // 18*32 uints

    // y0 aliases the y1 output region (chunk-ordered reads-before-writes).
    float* y0 = y1;

    for (int l = 0; l < 2; ++l) {
        const float* Ain  = l ? y0   : x;
        const float* wih  = l ? wih1 : wih0;
        const float* whh  = l ? whh1 : whh0;
        const float* bias = l ? b1   : b0;
        float* yout       = l ? y1   : y0;

        h_to_t<<<128, 256, 0, stream>>>(h0 + (size_t)l * BHq, hbuf);
        hipMemcpyAsync(cst, c0 + (size_t)l * BHq, BHq * sizeof(float),
                       hipMemcpyDeviceToDevice, stream);

        for (int ch = 0; ch < NCHq; ++ch) {
            const int s0 = ch * CHUNKq;
            gemm_xproj<<<dim3(32, 32), 256, 0, stream>>>(Ain, wih, bias,
                                                         gates, bar, s0);

            const float* garg = gates;
            const float* warg = whh;
            float* harg = hbuf;
            float* carg = cst;
            float* yarg = yout;
            unsigned int* barg = bar;
            int targ = s0;
            void* kp[] = {(void*)&garg, (void*)&warg, (void*)&harg,
                          (void*)&carg, (void*)&yarg, (void*)&barg,
                          (void*)&targ};
            hipLaunchCooperativeKernel((void*)lstm_scan, dim3(256), dim3(512),
                                       kp, 0, stream);
        }

        h_from_t<<<128, 256, 0, stream>>>(hbuf, hn + (size_t)l * BHq);
        hipMemcpyAsync(cn + (size_t)l * BHq, cst, BHq * sizeof(float),
                       hipMemcpyDeviceToDevice, stream);
    }
}